// Round 2
// baseline (2550.491 us; speedup 1.0000x reference)
//
#include <hip/hip_runtime.h>
#include <cstddef>

// ---------- types ----------
typedef _Float16 f16x8 __attribute__((ext_vector_type(8)));
typedef short    s16x8 __attribute__((ext_vector_type(8)));
typedef float    f32x4 __attribute__((ext_vector_type(4)));

#define MFMA_F16(a, b, c) __builtin_amdgcn_mfma_f32_16x16x32_f16((a), (b), (c), 0, 0, 0)

#if __has_builtin(__builtin_amdgcn_rcpf)
__device__ __forceinline__ float fast_rcp(float x) { return __builtin_amdgcn_rcpf(x); }
#else
__device__ __forceinline__ float fast_rcp(float x) { return 1.f / x; }
#endif

__device__ __forceinline__ f16x8 ld8(const short* p) {
  return __builtin_bit_cast(f16x8, *(const s16x8*)p);
}

// ---------- fp32 -> fp16 cast ----------
__global__ void cast_f16_kernel(const float* __restrict__ in, short* __restrict__ out, int n) {
  int i = blockIdx.x * blockDim.x + threadIdx.x;
  int stride = gridDim.x * blockDim.x;
  for (; i < n; i += stride)
    out[i] = __builtin_bit_cast(short, (_Float16)in[i]);
}

// ---------- fused GRU layer: input projection + recurrence ----------
// One wg = 16 batch rows; wave w owns JT j-tiles (16*JT hidden cols).
// Weights fp16, streamed from L2 every step. Recurrent h kept as fp16 hi/lo
// split in LDS (lo pre-scaled by 4096; recombined *2^-12 in fp32 epilogue);
// fp32 master h in registers (same lane owns same (bm,col) every step).
// Single __syncthreads per step via double-buffered h in LDS.
template <int HIN, int H, int NW, int JT, bool STORE_SEQ>
__global__ __launch_bounds__(NW * 64, (NW >= 4 ? NW / 4 : 1))
void gru_fused(const short* __restrict__ xin,   // [B,T,HIN] fp16 bits
               const short* __restrict__ Wih,   // [3H,HIN] fp16 bits
               const short* __restrict__ Whh,   // [3H,H] fp16 bits
               const float* __restrict__ b_ih,  // [3H]
               const float* __restrict__ b_hh,  // [3H]
               short* __restrict__ hseq,        // [B,T,H] fp16, if STORE_SEQ
               float* __restrict__ hlast) {     // [B,H] fp32, if !STORE_SEQ
  static_assert(NW * 16 * JT == H, "wave tiling must cover H");
  constexpr int T   = 256;
  constexpr int KSI = HIN / 32;
  constexpr int KS  = H / 32;
  constexpr int HP  = H + 8;  // +16B row pad; rows stay 16B-aligned
  __shared__ __align__(16) short hbuf[2][2][16][HP];  // [buf][hi/lo][row][col]

  const int lane = threadIdx.x & 63;
  const int wid  = threadIdx.x >> 6;
  const int p = lane & 15;
  const int q = lane >> 4;
  const int b0 = blockIdx.x * 16;
  const int j0 = wid * (16 * JT);

  // zero-init read buffer 0 (both hi and lo planes)
  for (int i = threadIdx.x; i < 2 * 16 * HP; i += NW * 64)
    (&hbuf[0][0][0][0])[i] = 0;

  // t-invariant per-lane constants: biases + weight row base pointers
  float brz_r[JT], brz_z[JT], bxn[JT], bhn[JT];
  const short *wih_r[JT], *wih_z[JT], *wih_n[JT];
  const short *whh_r[JT], *whh_z[JT], *whh_n[JT];
#pragma unroll
  for (int jt = 0; jt < JT; jt++) {
    const int col = j0 + jt * 16 + p;
    brz_r[jt] = b_ih[col] + b_hh[col];
    brz_z[jt] = b_ih[H + col] + b_hh[H + col];
    bxn[jt]   = b_ih[2 * H + col];
    bhn[jt]   = b_hh[2 * H + col];
    wih_r[jt] = Wih + (size_t)(0 * H + col) * HIN + q * 8;
    wih_z[jt] = Wih + (size_t)(1 * H + col) * HIN + q * 8;
    wih_n[jt] = Wih + (size_t)(2 * H + col) * HIN + q * 8;
    whh_r[jt] = Whh + (size_t)(0 * H + col) * H + q * 8;
    whh_z[jt] = Whh + (size_t)(1 * H + col) * H + q * 8;
    whh_n[jt] = Whh + (size_t)(2 * H + col) * H + q * 8;
  }
  float hprev[JT][4];
#pragma unroll
  for (int jt = 0; jt < JT; jt++)
#pragma unroll
    for (int r = 0; r < 4; r++) hprev[jt][r] = 0.f;

  const short* xp = xin + (size_t)(b0 + p) * T * HIN + q * 8;

  __syncthreads();

  for (int t = 0; t < T; t++) {
    const int cur = t & 1;
    const int nxt = cur ^ 1;

    // A-fragments: x_t (global, fp16 single) and h_{t-1} (LDS, hi/lo)
    f16x8 ax[KSI];
#pragma unroll
    for (int k = 0; k < KSI; k++) ax[k] = ld8(xp + k * 32);

    f16x8 ah[KS], al[KS];
#pragma unroll
    for (int k = 0; k < KS; k++) {
      ah[k] = ld8(&hbuf[cur][0][p][k * 32 + q * 8]);
      al[k] = ld8(&hbuf[cur][1][p][k * 32 + q * 8]);
    }

#pragma unroll
    for (int jt = 0; jt < JT; jt++) {
      f32x4 ar = {0.f, 0.f, 0.f, 0.f}, lr = {0.f, 0.f, 0.f, 0.f};
      f32x4 az = {0.f, 0.f, 0.f, 0.f}, lz = {0.f, 0.f, 0.f, 0.f};
      f32x4 xn = {0.f, 0.f, 0.f, 0.f};
      f32x4 an = {0.f, 0.f, 0.f, 0.f}, ln = {0.f, 0.f, 0.f, 0.f};
      // recurrence first (covers x-load latency); each W frag reused hi+lo
#pragma unroll
      for (int k = 0; k < KS; k++) {
        f16x8 w = ld8(whh_r[jt] + k * 32);
        ar = MFMA_F16(ah[k], w, ar);
        lr = MFMA_F16(al[k], w, lr);
      }
#pragma unroll
      for (int k = 0; k < KS; k++) {
        f16x8 w = ld8(whh_z[jt] + k * 32);
        az = MFMA_F16(ah[k], w, az);
        lz = MFMA_F16(al[k], w, lz);
      }
#pragma unroll
      for (int k = 0; k < KS; k++) {
        f16x8 w = ld8(whh_n[jt] + k * 32);
        an = MFMA_F16(ah[k], w, an);
        ln = MFMA_F16(al[k], w, ln);
      }
      // input projection
#pragma unroll
      for (int k = 0; k < KSI; k++) {
        ar = MFMA_F16(ax[k], ld8(wih_r[jt] + k * 32), ar);
        az = MFMA_F16(ax[k], ld8(wih_z[jt] + k * 32), az);
        xn = MFMA_F16(ax[k], ld8(wih_n[jt] + k * 32), xn);
      }
      // epilogue: C/D layout col = lane&15, row = q*4+r (batch)
      constexpr float LS = 1.f / 4096.f;
#pragma unroll
      for (int r = 0; r < 4; r++) {
        const int bm = q * 4 + r;
        const int col = j0 + jt * 16 + p;
        const float rpre = ar[r] + lr[r] * LS + brz_r[jt];
        const float zpre = az[r] + lz[r] * LS + brz_z[jt];
        const float ghn  = an[r] + ln[r] * LS + bhn[jt];
        const float rg = fast_rcp(1.f + __expf(-rpre));
        const float zg = fast_rcp(1.f + __expf(-zpre));
        const float narg = xn[r] + bxn[jt] + rg * ghn;
        const float e2 = __expf(2.f * narg);
        const float ng = 1.f - 2.f * fast_rcp(e2 + 1.f);  // tanh(narg)
        const float hnew = (1.f - zg) * ng + zg * hprev[jt][r];
        hprev[jt][r] = hnew;
        const _Float16 hi = (_Float16)hnew;
        const _Float16 lo = (_Float16)((hnew - (float)hi) * 4096.f);
        hbuf[nxt][0][bm][col] = __builtin_bit_cast(short, hi);
        hbuf[nxt][1][bm][col] = __builtin_bit_cast(short, lo);
        if (STORE_SEQ) {
          hseq[((size_t)(b0 + bm) * T + t) * H + col] = __builtin_bit_cast(short, hi);
        } else if (t == T - 1) {
          hlast[(size_t)(b0 + bm) * H + col] = hnew;
        }
      }
    }
    xp += HIN;
    __syncthreads();  // h writes (nxt) visible before next step's reads
  }
}

// ---------- dense head: out[b] = dot(hlast[b,:], Wd) + bd ----------
__global__ void dense_kernel(const float* __restrict__ hl, const float* __restrict__ Wd,
                             const float* __restrict__ bd, float* __restrict__ out) {
  const int b = blockIdx.x * 64 + threadIdx.x;
  float a = bd[0];
#pragma unroll
  for (int k = 0; k < 64; k++) a = fmaf(hl[b * 64 + k], Wd[k], a);
  out[b] = a;
}

// ---------- host ----------
extern "C" void kernel_launch(void* const* d_in, const int* in_sizes, int n_in,
                              void* d_out, int out_size, void* d_ws, size_t ws_size,
                              hipStream_t stream) {
  constexpr int B = 512, T = 256, F = 64;
  constexpr int H1 = 256, H2 = 128, H3 = 64;
  constexpr int M = B * T;

  const float* x     = (const float*)d_in[0];
  const float* W_ih1 = (const float*)d_in[1];
  const float* W_hh1 = (const float*)d_in[2];
  const float* b_ih1 = (const float*)d_in[3];
  const float* b_hh1 = (const float*)d_in[4];
  const float* W_ih2 = (const float*)d_in[5];
  const float* W_hh2 = (const float*)d_in[6];
  const float* b_ih2 = (const float*)d_in[7];
  const float* b_hh2 = (const float*)d_in[8];
  const float* W_ih3 = (const float*)d_in[9];
  const float* W_hh3 = (const float*)d_in[10];
  const float* b_ih3 = (const float*)d_in[11];
  const float* b_hh3 = (const float*)d_in[12];
  const float* W_d   = (const float*)d_in[13];
  const float* b_d   = (const float*)d_in[14];
  float* out = (float*)d_out;

  char* ws = (char*)d_ws;
  size_t off = 0;
  auto alloc = [&](size_t bytes) -> char* {
    char* pp = ws + off;
    off = (off + bytes + 255) & ~(size_t)255;
    return pp;
  };

  const int nx    = M * F;
  const int nwih1 = 3 * H1 * F,  nwhh1 = 3 * H1 * H1;
  const int nwih2 = 3 * H2 * H1, nwhh2 = 3 * H2 * H2;
  const int nwih3 = 3 * H3 * H2, nwhh3 = 3 * H3 * H3;

  // total workspace ~113 MiB
  short* xh    = (short*)alloc((size_t)nx * 2);          // 16 MiB
  short* wih1  = (short*)alloc((size_t)nwih1 * 2);
  short* whh1  = (short*)alloc((size_t)nwhh1 * 2);
  short* wih2  = (short*)alloc((size_t)nwih2 * 2);
  short* whh2  = (short*)alloc((size_t)nwhh2 * 2);
  short* wih3  = (short*)alloc((size_t)nwih3 * 2);
  short* whh3  = (short*)alloc((size_t)nwhh3 * 2);
  short* h1    = (short*)alloc((size_t)M * H1 * 2);      // 64 MiB
  short* h2    = (short*)alloc((size_t)M * H2 * 2);      // 32 MiB
  float* hlast = (float*)alloc((size_t)B * H3 * 4);
  (void)ws_size; (void)n_in; (void)in_sizes; (void)out_size;

  // casts to fp16
  cast_f16_kernel<<<2048, 256, 0, stream>>>(x, xh, nx);
  cast_f16_kernel<<<(nwih1 + 255) / 256, 256, 0, stream>>>(W_ih1, wih1, nwih1);
  cast_f16_kernel<<<(nwhh1 + 255) / 256, 256, 0, stream>>>(W_hh1, whh1, nwhh1);
  cast_f16_kernel<<<(nwih2 + 255) / 256, 256, 0, stream>>>(W_ih2, wih2, nwih2);
  cast_f16_kernel<<<(nwhh2 + 255) / 256, 256, 0, stream>>>(W_hh2, whh2, nwhh2);
  cast_f16_kernel<<<(nwih3 + 255) / 256, 256, 0, stream>>>(W_ih3, wih3, nwih3);
  cast_f16_kernel<<<(nwhh3 + 255) / 256, 256, 0, stream>>>(W_hh3, whh3, nwhh3);

  // fused layers: 32 wgs (batch tile 16), NW waves each
  gru_fused<64, 256, 8, 2, true><<<B / 16, 8 * 64, 0, stream>>>(
      xh, wih1, whh1, b_ih1, b_hh1, h1, nullptr);
  gru_fused<256, 128, 8, 1, true><<<B / 16, 8 * 64, 0, stream>>>(
      h1, wih2, whh2, b_ih2, b_hh2, h2, nullptr);
  gru_fused<128, 64, 4, 1, false><<<B / 16, 4 * 64, 0, stream>>>(
      h2, wih3, whh3, b_ih3, b_hh3, nullptr, hlast);

  dense_kernel<<<B / 64, 64, 0, stream>>>(hlast, W_d, b_d, out);
}

// Round 3
// 2396.532 us; speedup vs baseline: 1.0642x; 1.0642x over previous
//
#include <hip/hip_runtime.h>
#include <cstddef>

// ---------- types ----------
typedef _Float16 f16x8 __attribute__((ext_vector_type(8)));
typedef short    s16x8 __attribute__((ext_vector_type(8)));
typedef float    f32x4 __attribute__((ext_vector_type(4)));

#define MFMA_F16(a, b, c) __builtin_amdgcn_mfma_f32_16x16x32_f16((a), (b), (c), 0, 0, 0)

#if __has_builtin(__builtin_amdgcn_rcpf)
__device__ __forceinline__ float fast_rcp(float x) { return __builtin_amdgcn_rcpf(x); }
#else
__device__ __forceinline__ float fast_rcp(float x) { return 1.f / x; }
#endif

__device__ __forceinline__ f16x8 ld8(const short* p) {
  return __builtin_bit_cast(f16x8, *(const s16x8*)p);
}

// ---------- fp32 -> fp16 cast ----------
__global__ void cast_f16_kernel(const float* __restrict__ in, short* __restrict__ out, int n) {
  int i = blockIdx.x * blockDim.x + threadIdx.x;
  int stride = gridDim.x * blockDim.x;
  for (; i < n; i += stride)
    out[i] = __builtin_bit_cast(short, (_Float16)in[i]);
}

// ---------- fused GRU layer: input projection + recurrence ----------
// One wg = 16 batch rows; wave w owns JT j-tiles (16*JT hidden cols).
// Weights fp16. t-invariant weight fragments register-cached: all KCI wih
// k-frags and the first KCH whh k-frags per (jt,gate); the rest streamed from
// L2 each step. Recurrent h: fp16 hi + lo(n-gate correction, prescaled 4096)
// in double-buffered LDS; fp32 master h in registers. 1 syncthreads/step.
template <int HIN, int H, int NW, int JT, int KCI, int KCH, bool STORE_SEQ>
__global__ __launch_bounds__(NW * 64, (NW >= 8 ? 2 : 1))
void gru_fused(const short* __restrict__ xin,   // [B,T,HIN] fp16 bits
               const short* __restrict__ Wih,   // [3H,HIN] fp16 bits
               const short* __restrict__ Whh,   // [3H,H] fp16 bits
               const float* __restrict__ b_ih,  // [3H]
               const float* __restrict__ b_hh,  // [3H]
               short* __restrict__ hseq,        // [B,T,H] fp16, if STORE_SEQ
               float* __restrict__ hlast) {     // [B,H] fp32, if !STORE_SEQ
  static_assert(NW * 16 * JT == H, "wave tiling must cover H");
  constexpr int T   = 256;
  constexpr int KSI = HIN / 32;
  constexpr int KS  = H / 32;
  static_assert(KCI == KSI, "wih fully cached");
  static_assert(KCH <= KS, "");
  constexpr int HP  = H + 8;  // +16B row pad; rows stay 16B-aligned, 2-way banks
  __shared__ __align__(16) short hbuf[2][2][16][HP];  // [buf][hi/lo][row][col]

  const int lane = threadIdx.x & 63;
  const int wid  = threadIdx.x >> 6;
  const int p = lane & 15;
  const int q = lane >> 4;
  const int b0 = blockIdx.x * 16;
  const int j0 = wid * (16 * JT);

  // zero-init read buffer 0 (both hi and lo planes)
  for (int i = threadIdx.x; i < 2 * 16 * HP; i += NW * 64)
    (&hbuf[0][0][0][0])[i] = 0;

  // t-invariant per-lane constants: biases + weight row base pointers
  float brz_r[JT], brz_z[JT], bxn[JT], bhn[JT];
  const short* whh_p[JT][3];
#pragma unroll
  for (int jt = 0; jt < JT; jt++) {
    const int col = j0 + jt * 16 + p;
    brz_r[jt] = b_ih[col] + b_hh[col];
    brz_z[jt] = b_ih[H + col] + b_hh[H + col];
    bxn[jt]   = b_ih[2 * H + col];
    bhn[jt]   = b_hh[2 * H + col];
#pragma unroll
    for (int g = 0; g < 3; g++)
      whh_p[jt][g] = Whh + (size_t)(g * H + col) * H + q * 8;
  }

  // register-cached weight fragments (t-invariant)
  f16x8 wr_ih[JT][3][KCI];
  f16x8 wr_hh[JT][3][KCH > 0 ? KCH : 1];
#pragma unroll
  for (int jt = 0; jt < JT; jt++) {
    const int col = j0 + jt * 16 + p;
#pragma unroll
    for (int g = 0; g < 3; g++) {
      const short* wih_g = Wih + (size_t)(g * H + col) * HIN + q * 8;
#pragma unroll
      for (int k = 0; k < KCI; k++) wr_ih[jt][g][k] = ld8(wih_g + k * 32);
#pragma unroll
      for (int k = 0; k < KCH; k++) wr_hh[jt][g][k] = ld8(whh_p[jt][g] + k * 32);
    }
  }

  float hprev[JT][4];
#pragma unroll
  for (int jt = 0; jt < JT; jt++)
#pragma unroll
    for (int r = 0; r < 4; r++) hprev[jt][r] = 0.f;

  const short* xp = xin + (size_t)(b0 + p) * T * HIN + q * 8;

  __syncthreads();

  for (int t = 0; t < T; t++) {
    const int cur = t & 1;
    const int nxt = cur ^ 1;

    // A-fragments: x_t (global) and h_{t-1} hi/lo (LDS)
    f16x8 ax[KSI];
#pragma unroll
    for (int k = 0; k < KSI; k++) ax[k] = ld8(xp + k * 32);

    f16x8 ah[KS], al[KS];
#pragma unroll
    for (int k = 0; k < KS; k++) {
      ah[k] = ld8(&hbuf[cur][0][p][k * 32 + q * 8]);
      al[k] = ld8(&hbuf[cur][1][p][k * 32 + q * 8]);
    }

#pragma unroll
    for (int jt = 0; jt < JT; jt++) {
      f32x4 ar = {0.f, 0.f, 0.f, 0.f};
      f32x4 az = {0.f, 0.f, 0.f, 0.f};
      f32x4 xn = {0.f, 0.f, 0.f, 0.f};
      f32x4 an = {0.f, 0.f, 0.f, 0.f};
      f32x4 ln = {0.f, 0.f, 0.f, 0.f};
      // r gate (hi only)
#pragma unroll
      for (int k = 0; k < KS; k++) {
        f16x8 w;
        if (k < KCH) w = wr_hh[jt][0][k]; else w = ld8(whh_p[jt][0] + k * 32);
        ar = MFMA_F16(ah[k], w, ar);
      }
      // z gate (hi only)
#pragma unroll
      for (int k = 0; k < KS; k++) {
        f16x8 w;
        if (k < KCH) w = wr_hh[jt][1][k]; else w = ld8(whh_p[jt][1] + k * 32);
        az = MFMA_F16(ah[k], w, az);
      }
      // n gate (hi + lo correction; weight frag reused)
#pragma unroll
      for (int k = 0; k < KS; k++) {
        f16x8 w;
        if (k < KCH) w = wr_hh[jt][2][k]; else w = ld8(whh_p[jt][2] + k * 32);
        an = MFMA_F16(ah[k], w, an);
        ln = MFMA_F16(al[k], w, ln);
      }
      // input projection (weights fully register-resident)
#pragma unroll
      for (int k = 0; k < KSI; k++) {
        ar = MFMA_F16(ax[k], wr_ih[jt][0][k], ar);
        az = MFMA_F16(ax[k], wr_ih[jt][1][k], az);
        xn = MFMA_F16(ax[k], wr_ih[jt][2][k], xn);
      }
      // epilogue: C/D layout col = lane&15, row = q*4+r (batch)
      constexpr float LS = 1.f / 4096.f;
#pragma unroll
      for (int r = 0; r < 4; r++) {
        const int bm = q * 4 + r;
        const int col = j0 + jt * 16 + p;
        const float rpre = ar[r] + brz_r[jt];
        const float zpre = az[r] + brz_z[jt];
        const float ghn  = an[r] + ln[r] * LS + bhn[jt];
        const float rg = fast_rcp(1.f + __expf(-rpre));
        const float zg = fast_rcp(1.f + __expf(-zpre));
        const float narg = xn[r] + bxn[jt] + rg * ghn;
        const float e2 = __expf(2.f * narg);
        const float ng = 1.f - 2.f * fast_rcp(e2 + 1.f);  // tanh(narg)
        const float hnew = (1.f - zg) * ng + zg * hprev[jt][r];
        hprev[jt][r] = hnew;
        const _Float16 hi = (_Float16)hnew;
        const _Float16 lo = (_Float16)((hnew - (float)hi) * 4096.f);
        hbuf[nxt][0][bm][col] = __builtin_bit_cast(short, hi);
        hbuf[nxt][1][bm][col] = __builtin_bit_cast(short, lo);
        if (STORE_SEQ) {
          hseq[((size_t)(b0 + bm) * T + t) * H + col] = __builtin_bit_cast(short, hi);
        } else if (t == T - 1) {
          hlast[(size_t)(b0 + bm) * H + col] = hnew;
        }
      }
    }
    xp += HIN;
    __syncthreads();  // h writes (nxt) visible before next step's reads
  }
}

// ---------- dense head: out[b] = dot(hlast[b,:], Wd) + bd ----------
__global__ void dense_kernel(const float* __restrict__ hl, const float* __restrict__ Wd,
                             const float* __restrict__ bd, float* __restrict__ out) {
  const int b = blockIdx.x * 64 + threadIdx.x;
  float a = bd[0];
#pragma unroll
  for (int k = 0; k < 64; k++) a = fmaf(hl[b * 64 + k], Wd[k], a);
  out[b] = a;
}

// ---------- host ----------
extern "C" void kernel_launch(void* const* d_in, const int* in_sizes, int n_in,
                              void* d_out, int out_size, void* d_ws, size_t ws_size,
                              hipStream_t stream) {
  constexpr int B = 512, T = 256, F = 64;
  constexpr int H1 = 256, H2 = 128, H3 = 64;
  constexpr int M = B * T;

  const float* x     = (const float*)d_in[0];
  const float* W_ih1 = (const float*)d_in[1];
  const float* W_hh1 = (const float*)d_in[2];
  const float* b_ih1 = (const float*)d_in[3];
  const float* b_hh1 = (const float*)d_in[4];
  const float* W_ih2 = (const float*)d_in[5];
  const float* W_hh2 = (const float*)d_in[6];
  const float* b_ih2 = (const float*)d_in[7];
  const float* b_hh2 = (const float*)d_in[8];
  const float* W_ih3 = (const float*)d_in[9];
  const float* W_hh3 = (const float*)d_in[10];
  const float* b_ih3 = (const float*)d_in[11];
  const float* b_hh3 = (const float*)d_in[12];
  const float* W_d   = (const float*)d_in[13];
  const float* b_d   = (const float*)d_in[14];
  float* out = (float*)d_out;

  char* ws = (char*)d_ws;
  size_t off = 0;
  auto alloc = [&](size_t bytes) -> char* {
    char* pp = ws + off;
    off = (off + bytes + 255) & ~(size_t)255;
    return pp;
  };

  const int nx    = M * F;
  const int nwih1 = 3 * H1 * F,  nwhh1 = 3 * H1 * H1;
  const int nwih2 = 3 * H2 * H1, nwhh2 = 3 * H2 * H2;
  const int nwih3 = 3 * H3 * H2, nwhh3 = 3 * H3 * H3;

  short* xh    = (short*)alloc((size_t)nx * 2);
  short* wih1  = (short*)alloc((size_t)nwih1 * 2);
  short* whh1  = (short*)alloc((size_t)nwhh1 * 2);
  short* wih2  = (short*)alloc((size_t)nwih2 * 2);
  short* whh2  = (short*)alloc((size_t)nwhh2 * 2);
  short* wih3  = (short*)alloc((size_t)nwih3 * 2);
  short* whh3  = (short*)alloc((size_t)nwhh3 * 2);
  short* h1    = (short*)alloc((size_t)M * H1 * 2);
  short* h2    = (short*)alloc((size_t)M * H2 * 2);
  float* hlast = (float*)alloc((size_t)B * H3 * 4);
  (void)ws_size; (void)n_in; (void)in_sizes; (void)out_size;

  // casts to fp16
  cast_f16_kernel<<<2048, 256, 0, stream>>>(x, xh, nx);
  cast_f16_kernel<<<(nwih1 + 255) / 256, 256, 0, stream>>>(W_ih1, wih1, nwih1);
  cast_f16_kernel<<<(nwhh1 + 255) / 256, 256, 0, stream>>>(W_hh1, whh1, nwhh1);
  cast_f16_kernel<<<(nwih2 + 255) / 256, 256, 0, stream>>>(W_ih2, wih2, nwih2);
  cast_f16_kernel<<<(nwhh2 + 255) / 256, 256, 0, stream>>>(W_hh2, whh2, nwhh2);
  cast_f16_kernel<<<(nwih3 + 255) / 256, 256, 0, stream>>>(W_ih3, wih3, nwih3);
  cast_f16_kernel<<<(nwhh3 + 255) / 256, 256, 0, stream>>>(W_hh3, whh3, nwhh3);

  // fused layers; template args: HIN, H, NW, JT, KCI(wih frags), KCH(whh frags)
  // L1: cache wih fully (12 frags) + whh k<2 (12) -> stream 36 KB/wave/step
  gru_fused<64, 256, 8, 2, 2, 2, true><<<B / 16, 8 * 64, 0, stream>>>(
      xh, wih1, whh1, b_ih1, b_hh1, h1, nullptr);
  // L2: cache wih fully (24) + whh k<3 (9) -> stream 3 KB/wave/step
  gru_fused<256, 128, 8, 1, 8, 3, true><<<B / 16, 8 * 64, 0, stream>>>(
      h1, wih2, whh2, b_ih2, b_hh2, h2, nullptr);
  // L3: fully register-resident (NW=4 -> 1 wave/SIMD -> 512 VGPR budget)
  gru_fused<128, 64, 4, 1, 4, 2, false><<<B / 16, 4 * 64, 0, stream>>>(
      h2, wih3, whh3, b_ih3, b_hh3, nullptr, hlast);

  dense_kernel<<<B / 64, 64, 0, stream>>>(hlast, W_d, b_d, out);
}